// Round 2
// baseline (791.831 us; speedup 1.0000x reference)
//
#include <hip/hip_runtime.h>
#include <hip/hip_bf16.h>

// Problem constants
#define D_MODEL 2048
#define D_FF    8192
#define N_KV    256
#define S_TOP   16
#define M_ROWS  4096   // B*T = 4*1024

typedef __attribute__((ext_vector_type(8))) short bf16x8;   // 8 bf16 (4 VGPRs)
typedef __attribute__((ext_vector_type(4))) float f32x4;

typedef const __attribute__((address_space(1))) unsigned int* gp_t;
typedef __attribute__((address_space(3))) unsigned int* lp_t;

__device__ __forceinline__ void gload16(const void* g, void* l) {
  // async global->LDS, 16B per lane; LDS dest = wave-uniform base + lane*16
  __builtin_amdgcn_global_load_lds((gp_t)g, (lp_t)l, 16, 0, 0);
}

// ---------------- max|w| reduction (atomicMax on float bits; bits monotone for w>=0) -------
__global__ __launch_bounds__(256) void maxabs_kernel(const float4* __restrict__ w, int n4,
                                                     unsigned* __restrict__ out) {
  float m = 0.f;
  for (long i = (long)blockIdx.x * 256 + threadIdx.x; i < n4; i += (long)gridDim.x * 256) {
    float4 v = w[i];
    m = fmaxf(m, fmaxf(fmaxf(fabsf(v.x), fabsf(v.y)), fmaxf(fabsf(v.z), fabsf(v.w))));
  }
#pragma unroll
  for (int o = 32; o; o >>= 1) m = fmaxf(m, __shfl_down(m, o, 64));
  __shared__ float sm[4];
  int lane = threadIdx.x & 63, wid = threadIdx.x >> 6;
  if (lane == 0) sm[wid] = m;
  __syncthreads();
  if (threadIdx.x == 0) {
    float mm = fmaxf(fmaxf(sm[0], sm[1]), fmaxf(sm[2], sm[3]));
    atomicMax(out, __float_as_uint(mm));
  }
}

// ---------------- quantize + transpose: in [R][C] f32 -> out [C][R] ------------------------
// f32 variant stores the true dequantized value q/scale (K/V gather path).
__global__ __launch_bounds__(256) void quantT_f32(const float* __restrict__ in,
                                                  float* __restrict__ out, int R, int C,
                                                  const unsigned* __restrict__ maxbits) {
  __shared__ float tile[64][65];
  float scale = 127.f / fmaxf(__uint_as_float(*maxbits), 1e-8f);
  int r0 = blockIdx.y << 6, c0 = blockIdx.x << 6;
  int tx = threadIdx.x & 63, ty = threadIdx.x >> 6;
#pragma unroll
  for (int i = 0; i < 16; ++i) {
    int r = ty + (i << 2);
    float v = in[(long)(r0 + r) * C + c0 + tx];
    tile[r][tx] = fminf(fmaxf(rintf(v * scale), -128.f), 127.f);
  }
  __syncthreads();
#pragma unroll
  for (int i = 0; i < 16; ++i) {
    int c = ty + (i << 2);
    out[(long)(c0 + c) * R + r0 + tx] = tile[tx][c] / scale;
  }
}

// bf16 variant stores the INTEGER code (exact in bf16, |q|<=128); scale folded into epilogue.
__global__ __launch_bounds__(256) void quantT_bf16(const float* __restrict__ in,
                                                   __hip_bfloat16* __restrict__ out, int R, int C,
                                                   const unsigned* __restrict__ maxbits) {
  __shared__ float tile[64][65];
  float scale = 127.f / fmaxf(__uint_as_float(*maxbits), 1e-8f);
  int r0 = blockIdx.y << 6, c0 = blockIdx.x << 6;
  int tx = threadIdx.x & 63, ty = threadIdx.x >> 6;
#pragma unroll
  for (int i = 0; i < 16; ++i) {
    int r = ty + (i << 2);
    float v = in[(long)(r0 + r) * C + c0 + tx];
    tile[r][tx] = fminf(fmaxf(rintf(v * scale), -128.f), 127.f);
  }
  __syncthreads();
#pragma unroll
  for (int i = 0; i < 16; ++i) {
    int c = ty + (i << 2);
    out[(long)(c0 + c) * R + r0 + tx] = __float2bfloat16(tile[tx][c]);
  }
}

// ---------------- gather-attention: one block per (b,t) ------------------------------------
__global__ __launch_bounds__(256) void attn_kernel(const float* __restrict__ x,
                                                   const int* __restrict__ idx,
                                                   const float* __restrict__ KqT,
                                                   const float* __restrict__ VqT,
                                                   __hip_bfloat16* __restrict__ combHi,
                                                   __hip_bfloat16* __restrict__ combLo) {
  int bt = blockIdx.x;
  const float* xr = x + (long)bt * D_MODEL;
  __shared__ int sidx[S_TOP];
  __shared__ float sred[S_TOP][4];
  __shared__ float sp[S_TOP];
  int t = threadIdx.x, lane = t & 63, wid = t >> 6;
  if (t < S_TOP) sidx[t] = idx[(long)bt * S_TOP + t];
  __syncthreads();
  float xv[8];
#pragma unroll
  for (int j = 0; j < 8; ++j) xv[j] = xr[t + (j << 8)];
#pragma unroll
  for (int s = 0; s < S_TOP; ++s) {
    const float* kc = KqT + (long)sidx[s] * D_MODEL;
    float a = 0.f;
#pragma unroll
    for (int j = 0; j < 8; ++j) a += xv[j] * kc[t + (j << 8)];
#pragma unroll
    for (int o = 32; o; o >>= 1) a += __shfl_down(a, o, 64);
    if (lane == 0) sred[s][wid] = a;
  }
  __syncthreads();
  if (t < S_TOP) {
    float sc = sred[t][0] + sred[t][1] + sred[t][2] + sred[t][3];
    float mx = sc;
#pragma unroll
    for (int o = 8; o; o >>= 1) mx = fmaxf(mx, __shfl_xor(mx, o, 16));
    float e = __expf(sc - mx);
    float su = e;
#pragma unroll
    for (int o = 8; o; o >>= 1) su += __shfl_xor(su, o, 16);
    sp[t] = e / su;
  }
  __syncthreads();
  float p[S_TOP];
#pragma unroll
  for (int s = 0; s < S_TOP; ++s) p[s] = sp[s];
#pragma unroll
  for (int j = 0; j < 8; ++j) {
    int d = t + (j << 8);
    float c = 0.f;
#pragma unroll
    for (int s = 0; s < S_TOP; ++s) c += p[s] * VqT[(long)sidx[s] * D_MODEL + d];
    __hip_bfloat16 hi = __float2bfloat16(c);
    long off = (long)bt * D_MODEL + d;
    combHi[off] = hi;
    combLo[off] = __float2bfloat16(c - __bfloat162float(hi));
  }
}

// ---------------- GEMM: C[M][N] = (Ahi + Alo) @ Bt^T * (max/127) ---------------------------
// Ahi/Alo: [M][KT] bf16 (hi/lo split activations). Bt: [N][KT] bf16 integer codes.
// OutT=float: write raw f32. OutT=bf16: write hi plane (+ lo plane if SPLIT).
// 128x128 tile, BK=64, 4 waves (2x2 of 64x64), m97-style global_load_lds staging.
template <int KT, bool SPLIT, bool USE_ALO, typename OutT>
__global__ __launch_bounds__(256) void gemm_qw(const __hip_bfloat16* __restrict__ Ahi,
                                               const __hip_bfloat16* __restrict__ Alo,
                                               const __hip_bfloat16* __restrict__ Bt,
                                               const unsigned* __restrict__ maxbits,
                                               OutT* __restrict__ outHi,
                                               __hip_bfloat16* __restrict__ outLo, int Ntot) {
  __shared__ __hip_bfloat16 lAhi[128 * 64];
  __shared__ __hip_bfloat16 lAlo[USE_ALO ? 128 * 64 : 1];
  __shared__ __hip_bfloat16 lB[128 * 64];
  const int t = threadIdx.x;
  const int lane = t & 63, wid = t >> 6;
  const int wr = (wid >> 1) << 6, wc = (wid & 1) << 6;
  const long m0 = (long)blockIdx.y << 7;
  const long n0 = (long)blockIdx.x << 7;
  const __hip_bfloat16* gA = Ahi + m0 * KT;
  const __hip_bfloat16* gL = USE_ALO ? (Alo + m0 * KT) : nullptr;
  const __hip_bfloat16* gB = Bt + n0 * KT;

  f32x4 acc[4][4] = {};

  const int srow = t >> 3;         // 0..31
  const int scol = (t & 7) << 3;   // 0,8,..,56 (elements)

  for (int kt = 0; kt < KT; kt += 64) {
#pragma unroll
    for (int it = 0; it < 4; ++it) {
      int row = (it << 5) + srow;
      long goff = (long)row * KT + kt + scol;
      int loff = ((it << 8) + t) << 4;  // bytes; wave-uniform base + lane*16 (linear)
      gload16(gA + goff, (char*)lAhi + loff);
      if (USE_ALO) gload16(gL + goff, (char*)lAlo + loff);
      gload16(gB + goff, (char*)lB + loff);
    }
    __syncthreads();
#pragma unroll
    for (int kk = 0; kk < 2; ++kk) {
      const int krow = (kk << 5) + ((lane >> 4) << 3);
      bf16x8 aH[4], bF[4];
#pragma unroll
      for (int i = 0; i < 4; ++i) {
        aH[i] = *(const bf16x8*)(lAhi + ((wr + (i << 4) + (lane & 15)) << 6) + krow);
        bF[i] = *(const bf16x8*)(lB + ((wc + (i << 4) + (lane & 15)) << 6) + krow);
      }
#pragma unroll
      for (int i = 0; i < 4; ++i)
#pragma unroll
        for (int j = 0; j < 4; ++j)
          acc[i][j] = __builtin_amdgcn_mfma_f32_16x16x32_bf16(aH[i], bF[j], acc[i][j], 0, 0, 0);
      if (USE_ALO) {
        bf16x8 aL[4];
#pragma unroll
        for (int i = 0; i < 4; ++i)
          aL[i] = *(const bf16x8*)(lAlo + ((wr + (i << 4) + (lane & 15)) << 6) + krow);
#pragma unroll
        for (int i = 0; i < 4; ++i)
#pragma unroll
          for (int j = 0; j < 4; ++j)
            acc[i][j] = __builtin_amdgcn_mfma_f32_16x16x32_bf16(aL[i], bF[j], acc[i][j], 0, 0, 0);
      }
    }
    __syncthreads();
  }

  float inv = fmaxf(__uint_as_float(*maxbits), 1e-8f) * (1.f / 127.f);  // = 1/scale
#pragma unroll
  for (int i = 0; i < 4; ++i) {
#pragma unroll
    for (int j = 0; j < 4; ++j) {
#pragma unroll
      for (int r = 0; r < 4; ++r) {
        long row = m0 + wr + (i << 4) + ((lane >> 4) << 2) + r;  // C/D: row=(lane>>4)*4+reg
        long col = n0 + wc + (j << 4) + (lane & 15);             //      col=lane&15
        float h = acc[i][j][r] * inv;
        long off = row * Ntot + col;
        if constexpr (__is_same(OutT, float)) {
          outHi[off] = h;
        } else {
          __hip_bfloat16 hi = __float2bfloat16(h);
          outHi[off] = hi;
          if (SPLIT) outLo[off] = __float2bfloat16(h - __bfloat162float(hi));
        }
      }
    }
  }
}

extern "C" void kernel_launch(void* const* d_in, const int* in_sizes, int n_in, void* d_out,
                              int out_size, void* d_ws, size_t ws_size, hipStream_t stream) {
  const float* x = (const float*)d_in[0];
  const int* idx = (const int*)d_in[1];
  const float* W_K = (const float*)d_in[2];
  const float* W_V = (const float*)d_in[3];
  const float* W_in = (const float*)d_in[4];
  const float* W_out = (const float*)d_in[5];
  float* out = (float*)d_out;  // reference output dtype is float32

  char* ws = (char*)d_ws;
  size_t off = 0;
  unsigned* maxb = (unsigned*)(ws + off); off += 256;
  float* KqT = (float*)(ws + off); off += (size_t)N_KV * D_MODEL * 4;   // [256][2048] f32
  float* VqT = (float*)(ws + off); off += (size_t)N_KV * D_MODEL * 4;
  __hip_bfloat16* QinT = (__hip_bfloat16*)(ws + off); off += (size_t)D_FF * D_MODEL * 2;  // [8192][2048]
  // comb (hi+lo) region; QoutT overlays it after GEMM1 (comb is dead by then)
  __hip_bfloat16* combHi = (__hip_bfloat16*)(ws + off);
  __hip_bfloat16* QoutT = (__hip_bfloat16*)(ws + off);
  __hip_bfloat16* combLo = (__hip_bfloat16*)(ws + off + (size_t)M_ROWS * D_MODEL * 2);
  off += (size_t)M_ROWS * D_MODEL * 2 * 2;  // 33.5 MB (== QoutT size, overlay safe)
  __hip_bfloat16* hidHi = (__hip_bfloat16*)(ws + off); off += (size_t)M_ROWS * D_FF * 2;  // 67 MB
  bool useLo = (off + (size_t)M_ROWS * D_FF * 2) <= ws_size;
  __hip_bfloat16* hidLo = useLo ? (__hip_bfloat16*)(ws + off) : nullptr;

  hipMemsetAsync(maxb, 0, 16, stream);
  maxabs_kernel<<<512, 256, 0, stream>>>((const float4*)W_K, (D_MODEL * N_KV) / 4, maxb + 0);
  maxabs_kernel<<<512, 256, 0, stream>>>((const float4*)W_V, (D_MODEL * N_KV) / 4, maxb + 1);
  maxabs_kernel<<<1024, 256, 0, stream>>>((const float4*)W_in, (D_MODEL * D_FF) / 4, maxb + 2);
  maxabs_kernel<<<1024, 256, 0, stream>>>((const float4*)W_out, (D_FF * D_MODEL) / 4, maxb + 3);

  quantT_f32<<<dim3(N_KV / 64, D_MODEL / 64), 256, 0, stream>>>(W_K, KqT, D_MODEL, N_KV, maxb + 0);
  quantT_f32<<<dim3(N_KV / 64, D_MODEL / 64), 256, 0, stream>>>(W_V, VqT, D_MODEL, N_KV, maxb + 1);
  quantT_bf16<<<dim3(D_FF / 64, D_MODEL / 64), 256, 0, stream>>>(W_in, QinT, D_MODEL, D_FF, maxb + 2);

  attn_kernel<<<M_ROWS, 256, 0, stream>>>(x, idx, KqT, VqT, combHi, combLo);

  if (useLo)
    gemm_qw<D_MODEL, true, true, __hip_bfloat16><<<dim3(D_FF / 128, M_ROWS / 128), 256, 0, stream>>>(
        combHi, combLo, QinT, maxb + 2, hidHi, hidLo, D_FF);
  else
    gemm_qw<D_MODEL, false, true, __hip_bfloat16><<<dim3(D_FF / 128, M_ROWS / 128), 256, 0, stream>>>(
        combHi, combLo, QinT, maxb + 2, hidHi, nullptr, D_FF);

  quantT_bf16<<<dim3(D_MODEL / 64, D_FF / 64), 256, 0, stream>>>(W_out, QoutT, D_FF, D_MODEL, maxb + 3);

  if (useLo)
    gemm_qw<D_FF, false, true, float><<<dim3(D_MODEL / 128, M_ROWS / 128), 256, 0, stream>>>(
        hidHi, hidLo, QoutT, maxb + 3, out, nullptr, D_MODEL);
  else
    gemm_qw<D_FF, false, false, float><<<dim3(D_MODEL / 128, M_ROWS / 128), 256, 0, stream>>>(
        hidHi, nullptr, QoutT, maxb + 3, out, nullptr, D_MODEL);
}

// Round 3
// 599.410 us; speedup vs baseline: 1.3210x; 1.3210x over previous
//
#include <hip/hip_runtime.h>
#include <hip/hip_bf16.h>

// Problem constants
#define D_MODEL 2048
#define D_FF    8192
#define N_KV    256
#define S_TOP   16
#define M_ROWS  4096   // B*T = 4*1024

typedef __attribute__((ext_vector_type(8))) short bf16x8;   // 8 bf16 (4 VGPRs)
typedef __attribute__((ext_vector_type(4))) float f32x4;

typedef const __attribute__((address_space(1))) unsigned int* gp_t;
typedef __attribute__((address_space(3))) unsigned int* lp_t;

__device__ __forceinline__ void gload16(const void* g, void* l) {
  // async global->LDS, 16B per lane; LDS dest = wave-uniform base + lane*16
  __builtin_amdgcn_global_load_lds((gp_t)g, (lp_t)l, 16, 0, 0);
}

// ---------------- max|w| reduction (atomicMax on float bits; bits monotone for w>=0) -------
__global__ __launch_bounds__(256) void maxabs_kernel(const float4* __restrict__ w, int n4,
                                                     unsigned* __restrict__ out) {
  float m = 0.f;
  for (long i = (long)blockIdx.x * 256 + threadIdx.x; i < n4; i += (long)gridDim.x * 256) {
    float4 v = w[i];
    m = fmaxf(m, fmaxf(fmaxf(fabsf(v.x), fabsf(v.y)), fmaxf(fabsf(v.z), fabsf(v.w))));
  }
#pragma unroll
  for (int o = 32; o; o >>= 1) m = fmaxf(m, __shfl_down(m, o, 64));
  __shared__ float sm[4];
  int lane = threadIdx.x & 63, wid = threadIdx.x >> 6;
  if (lane == 0) sm[wid] = m;
  __syncthreads();
  if (threadIdx.x == 0) {
    float mm = fmaxf(fmaxf(sm[0], sm[1]), fmaxf(sm[2], sm[3]));
    atomicMax(out, __float_as_uint(mm));
  }
}

// ---------------- quantize + transpose: in [R][C] f32 -> out [C][R] ------------------------
// f32 variant stores the true dequantized value q/scale (K/V gather path).
__global__ __launch_bounds__(256) void quantT_f32(const float* __restrict__ in,
                                                  float* __restrict__ out, int R, int C,
                                                  const unsigned* __restrict__ maxbits) {
  __shared__ float tile[64][65];
  float scale = 127.f / fmaxf(__uint_as_float(*maxbits), 1e-8f);
  int r0 = blockIdx.y << 6, c0 = blockIdx.x << 6;
  int tx = threadIdx.x & 63, ty = threadIdx.x >> 6;
#pragma unroll
  for (int i = 0; i < 16; ++i) {
    int r = ty + (i << 2);
    float v = in[(long)(r0 + r) * C + c0 + tx];
    tile[r][tx] = fminf(fmaxf(rintf(v * scale), -128.f), 127.f);
  }
  __syncthreads();
#pragma unroll
  for (int i = 0; i < 16; ++i) {
    int c = ty + (i << 2);
    out[(long)(c0 + c) * R + r0 + tx] = tile[tx][c] / scale;
  }
}

// bf16 variant stores the INTEGER code (exact in bf16, |q|<=128); scale folded into epilogue.
__global__ __launch_bounds__(256) void quantT_bf16(const float* __restrict__ in,
                                                   __hip_bfloat16* __restrict__ out, int R, int C,
                                                   const unsigned* __restrict__ maxbits) {
  __shared__ float tile[64][65];
  float scale = 127.f / fmaxf(__uint_as_float(*maxbits), 1e-8f);
  int r0 = blockIdx.y << 6, c0 = blockIdx.x << 6;
  int tx = threadIdx.x & 63, ty = threadIdx.x >> 6;
#pragma unroll
  for (int i = 0; i < 16; ++i) {
    int r = ty + (i << 2);
    float v = in[(long)(r0 + r) * C + c0 + tx];
    tile[r][tx] = fminf(fmaxf(rintf(v * scale), -128.f), 127.f);
  }
  __syncthreads();
#pragma unroll
  for (int i = 0; i < 16; ++i) {
    int c = ty + (i << 2);
    out[(long)(c0 + c) * R + r0 + tx] = __float2bfloat16(tile[tx][c]);
  }
}

// ---------------- gather-attention: one block per (b,t) ------------------------------------
__global__ __launch_bounds__(256) void attn_kernel(const float* __restrict__ x,
                                                   const int* __restrict__ idx,
                                                   const float* __restrict__ KqT,
                                                   const float* __restrict__ VqT,
                                                   __hip_bfloat16* __restrict__ combHi) {
  int bt = blockIdx.x;
  const float* xr = x + (long)bt * D_MODEL;
  __shared__ int sidx[S_TOP];
  __shared__ float sred[S_TOP][4];
  __shared__ float sp[S_TOP];
  int t = threadIdx.x, lane = t & 63, wid = t >> 6;
  if (t < S_TOP) sidx[t] = idx[(long)bt * S_TOP + t];
  __syncthreads();
  float xv[8];
#pragma unroll
  for (int j = 0; j < 8; ++j) xv[j] = xr[t + (j << 8)];
#pragma unroll
  for (int s = 0; s < S_TOP; ++s) {
    const float* kc = KqT + (long)sidx[s] * D_MODEL;
    float a = 0.f;
#pragma unroll
    for (int j = 0; j < 8; ++j) a += xv[j] * kc[t + (j << 8)];
#pragma unroll
    for (int o = 32; o; o >>= 1) a += __shfl_down(a, o, 64);
    if (lane == 0) sred[s][wid] = a;
  }
  __syncthreads();
  if (t < S_TOP) {
    float sc = sred[t][0] + sred[t][1] + sred[t][2] + sred[t][3];
    float mx = sc;
#pragma unroll
    for (int o = 8; o; o >>= 1) mx = fmaxf(mx, __shfl_xor(mx, o, 16));
    float e = __expf(sc - mx);
    float su = e;
#pragma unroll
    for (int o = 8; o; o >>= 1) su += __shfl_xor(su, o, 16);
    sp[t] = e / su;
  }
  __syncthreads();
  float p[S_TOP];
#pragma unroll
  for (int s = 0; s < S_TOP; ++s) p[s] = sp[s];
#pragma unroll
  for (int j = 0; j < 8; ++j) {
    int d = t + (j << 8);
    float c = 0.f;
#pragma unroll
    for (int s = 0; s < S_TOP; ++s) c += p[s] * VqT[(long)sidx[s] * D_MODEL + d];
    combHi[(long)bt * D_MODEL + d] = __float2bfloat16(c);
  }
}

// ---------------- GEMM: C[M][N] = (Ahi [+ Alo]) @ Bt^T * (max/127) -------------------------
// Ahi/Alo: [M][KT] bf16 activations. Bt: [N][KT] bf16 integer codes (exact).
// OutT=float: write raw f32. OutT=bf16: write hi plane (+ lo plane if SPLIT).
// 128x128 tile, BK=64, 4 waves (2x2 of 64x64), m97-style global_load_lds staging.
template <int KT, bool SPLIT, bool USE_ALO, typename OutT>
__global__ __launch_bounds__(256) void gemm_qw(const __hip_bfloat16* __restrict__ Ahi,
                                               const __hip_bfloat16* __restrict__ Alo,
                                               const __hip_bfloat16* __restrict__ Bt,
                                               const unsigned* __restrict__ maxbits,
                                               OutT* __restrict__ outHi,
                                               __hip_bfloat16* __restrict__ outLo, int Ntot) {
  __shared__ __hip_bfloat16 lAhi[128 * 64];
  __shared__ __hip_bfloat16 lAlo[USE_ALO ? 128 * 64 : 1];
  __shared__ __hip_bfloat16 lB[128 * 64];
  const int t = threadIdx.x;
  const int lane = t & 63, wid = t >> 6;
  const int wr = (wid >> 1) << 6, wc = (wid & 1) << 6;
  const long m0 = (long)blockIdx.y << 7;
  const long n0 = (long)blockIdx.x << 7;
  const __hip_bfloat16* gA = Ahi + m0 * KT;
  const __hip_bfloat16* gL = USE_ALO ? (Alo + m0 * KT) : nullptr;
  const __hip_bfloat16* gB = Bt + n0 * KT;

  f32x4 acc[4][4] = {};

  const int srow = t >> 3;         // 0..31
  const int scol = (t & 7) << 3;   // 0,8,..,56 (elements)

  for (int kt = 0; kt < KT; kt += 64) {
#pragma unroll
    for (int it = 0; it < 4; ++it) {
      int row = (it << 5) + srow;
      long goff = (long)row * KT + kt + scol;
      int loff = ((it << 8) + t) << 4;  // bytes; wave-uniform base + lane*16 (linear)
      gload16(gA + goff, (char*)lAhi + loff);
      if (USE_ALO) gload16(gL + goff, (char*)lAlo + loff);
      gload16(gB + goff, (char*)lB + loff);
    }
    __syncthreads();
#pragma unroll
    for (int kk = 0; kk < 2; ++kk) {
      const int krow = (kk << 5) + ((lane >> 4) << 3);
      bf16x8 aH[4], bF[4];
#pragma unroll
      for (int i = 0; i < 4; ++i) {
        aH[i] = *(const bf16x8*)(lAhi + ((wr + (i << 4) + (lane & 15)) << 6) + krow);
        bF[i] = *(const bf16x8*)(lB + ((wc + (i << 4) + (lane & 15)) << 6) + krow);
      }
#pragma unroll
      for (int i = 0; i < 4; ++i)
#pragma unroll
        for (int j = 0; j < 4; ++j)
          acc[i][j] = __builtin_amdgcn_mfma_f32_16x16x32_bf16(aH[i], bF[j], acc[i][j], 0, 0, 0);
      if (USE_ALO) {
        bf16x8 aL[4];
#pragma unroll
        for (int i = 0; i < 4; ++i)
          aL[i] = *(const bf16x8*)(lAlo + ((wr + (i << 4) + (lane & 15)) << 6) + krow);
#pragma unroll
        for (int i = 0; i < 4; ++i)
#pragma unroll
          for (int j = 0; j < 4; ++j)
            acc[i][j] = __builtin_amdgcn_mfma_f32_16x16x32_bf16(aL[i], bF[j], acc[i][j], 0, 0, 0);
      }
    }
    __syncthreads();
  }

  float inv = fmaxf(__uint_as_float(*maxbits), 1e-8f) * (1.f / 127.f);  // = 1/scale
#pragma unroll
  for (int i = 0; i < 4; ++i) {
#pragma unroll
    for (int j = 0; j < 4; ++j) {
#pragma unroll
      for (int r = 0; r < 4; ++r) {
        long row = m0 + wr + (i << 4) + ((lane >> 4) << 2) + r;  // C/D: row=(lane>>4)*4+reg
        long col = n0 + wc + (j << 4) + (lane & 15);             //      col=lane&15
        float h = acc[i][j][r] * inv;
        long off = row * Ntot + col;
        if constexpr (__is_same(OutT, float)) {
          outHi[off] = h;
        } else {
          __hip_bfloat16 hi = __float2bfloat16(h);
          outHi[off] = hi;
          if (SPLIT) outLo[off] = __float2bfloat16(h - __bfloat162float(hi));
        }
      }
    }
  }
}

extern "C" void kernel_launch(void* const* d_in, const int* in_sizes, int n_in, void* d_out,
                              int out_size, void* d_ws, size_t ws_size, hipStream_t stream) {
  const float* x = (const float*)d_in[0];
  const int* idx = (const int*)d_in[1];
  const float* W_K = (const float*)d_in[2];
  const float* W_V = (const float*)d_in[3];
  const float* W_in = (const float*)d_in[4];
  const float* W_out = (const float*)d_in[5];
  float* out = (float*)d_out;  // reference output dtype is float32

  char* ws = (char*)d_ws;
  size_t off = 0;
  unsigned* maxb = (unsigned*)(ws + off); off += 256;
  float* KqT = (float*)(ws + off); off += (size_t)N_KV * D_MODEL * 4;   // [256][2048] f32
  float* VqT = (float*)(ws + off); off += (size_t)N_KV * D_MODEL * 4;
  __hip_bfloat16* QinT = (__hip_bfloat16*)(ws + off); off += (size_t)D_FF * D_MODEL * 2;  // [8192][2048]
  // comb region; QoutT overlays it after GEMM1 (comb dead by then; QoutT is 2x comb size)
  __hip_bfloat16* combHi = (__hip_bfloat16*)(ws + off);
  __hip_bfloat16* QoutT = (__hip_bfloat16*)(ws + off);
  off += (size_t)D_MODEL * D_FF * 2;  // 33.5 MB (QoutT [2048][8192])
  __hip_bfloat16* hidHi = (__hip_bfloat16*)(ws + off); off += (size_t)M_ROWS * D_FF * 2;  // 67 MB

  hipMemsetAsync(maxb, 0, 16, stream);
  maxabs_kernel<<<512, 256, 0, stream>>>((const float4*)W_K, (D_MODEL * N_KV) / 4, maxb + 0);
  maxabs_kernel<<<512, 256, 0, stream>>>((const float4*)W_V, (D_MODEL * N_KV) / 4, maxb + 1);
  maxabs_kernel<<<1024, 256, 0, stream>>>((const float4*)W_in, (D_MODEL * D_FF) / 4, maxb + 2);
  maxabs_kernel<<<1024, 256, 0, stream>>>((const float4*)W_out, (D_FF * D_MODEL) / 4, maxb + 3);

  quantT_f32<<<dim3(N_KV / 64, D_MODEL / 64), 256, 0, stream>>>(W_K, KqT, D_MODEL, N_KV, maxb + 0);
  quantT_f32<<<dim3(N_KV / 64, D_MODEL / 64), 256, 0, stream>>>(W_V, VqT, D_MODEL, N_KV, maxb + 1);
  quantT_bf16<<<dim3(D_FF / 64, D_MODEL / 64), 256, 0, stream>>>(W_in, QinT, D_MODEL, D_FF, maxb + 2);

  attn_kernel<<<M_ROWS, 256, 0, stream>>>(x, idx, KqT, VqT, combHi);

  // bf16-only activations (lo-planes dropped; ~10x absmax margin measured with hi/lo)
  gemm_qw<D_MODEL, false, false, __hip_bfloat16><<<dim3(D_FF / 128, M_ROWS / 128), 256, 0, stream>>>(
      combHi, nullptr, QinT, maxb + 2, hidHi, nullptr, D_FF);

  quantT_bf16<<<dim3(D_MODEL / 64, D_FF / 64), 256, 0, stream>>>(W_out, QoutT, D_FF, D_MODEL, maxb + 3);

  gemm_qw<D_FF, false, false, float><<<dim3(D_MODEL / 128, M_ROWS / 128), 256, 0, stream>>>(
      hidHi, nullptr, QoutT, maxb + 3, out, nullptr, D_MODEL);
}

// Round 4
// 521.546 us; speedup vs baseline: 1.5182x; 1.1493x over previous
//
#include <hip/hip_runtime.h>
#include <hip/hip_bf16.h>

// Problem constants
#define D_MODEL 2048
#define D_FF    8192
#define N_KV    256
#define S_TOP   16
#define M_ROWS  4096   // B*T = 4*1024

typedef __attribute__((ext_vector_type(8))) short bf16x8;   // 8 bf16 (4 VGPRs)
typedef __attribute__((ext_vector_type(4))) float f32x4;
typedef __hip_bfloat16 bf16;

typedef const __attribute__((address_space(1))) unsigned int* gp_t;
typedef __attribute__((address_space(3))) unsigned int* lp_t;

__device__ __forceinline__ void gload16(const void* g, void* l) {
  // async global->LDS, 16B per lane; LDS dest = wave-uniform base + lane*16
  __builtin_amdgcn_global_load_lds((gp_t)g, (lp_t)l, 16, 0, 0);
}

// ---------------- max|w| reduction (atomicMax on float bits; bits monotone for w>=0) -------
__global__ __launch_bounds__(256) void maxabs_kernel(const float4* __restrict__ w, int n4,
                                                     unsigned* __restrict__ out) {
  float m = 0.f;
  for (long i = (long)blockIdx.x * 256 + threadIdx.x; i < n4; i += (long)gridDim.x * 256) {
    float4 v = w[i];
    m = fmaxf(m, fmaxf(fmaxf(fabsf(v.x), fabsf(v.y)), fmaxf(fabsf(v.z), fabsf(v.w))));
  }
#pragma unroll
  for (int o = 32; o; o >>= 1) m = fmaxf(m, __shfl_down(m, o, 64));
  __shared__ float sm[4];
  int lane = threadIdx.x & 63, wid = threadIdx.x >> 6;
  if (lane == 0) sm[wid] = m;
  __syncthreads();
  if (threadIdx.x == 0) {
    float mm = fmaxf(fmaxf(sm[0], sm[1]), fmaxf(sm[2], sm[3]));
    atomicMax(out, __float_as_uint(mm));
  }
}

// ---------------- quantize + transpose: in [R][C] f32 -> out [C][R] ------------------------
__global__ __launch_bounds__(256) void quantT_f32(const float* __restrict__ in,
                                                  float* __restrict__ out, int R, int C,
                                                  const unsigned* __restrict__ maxbits) {
  __shared__ float tile[64][65];
  float scale = 127.f / fmaxf(__uint_as_float(*maxbits), 1e-8f);
  int r0 = blockIdx.y << 6, c0 = blockIdx.x << 6;
  int tx = threadIdx.x & 63, ty = threadIdx.x >> 6;
#pragma unroll
  for (int i = 0; i < 16; ++i) {
    int r = ty + (i << 2);
    float v = in[(long)(r0 + r) * C + c0 + tx];
    tile[r][tx] = fminf(fmaxf(rintf(v * scale), -128.f), 127.f);
  }
  __syncthreads();
#pragma unroll
  for (int i = 0; i < 16; ++i) {
    int c = ty + (i << 2);
    out[(long)(c0 + c) * R + r0 + tx] = tile[tx][c] / scale;
  }
}

// bf16 variant stores the INTEGER code (exact in bf16, |q|<=128); scale folded into epilogue.
__global__ __launch_bounds__(256) void quantT_bf16(const float* __restrict__ in,
                                                   bf16* __restrict__ out, int R, int C,
                                                   const unsigned* __restrict__ maxbits) {
  __shared__ float tile[64][65];
  float scale = 127.f / fmaxf(__uint_as_float(*maxbits), 1e-8f);
  int r0 = blockIdx.y << 6, c0 = blockIdx.x << 6;
  int tx = threadIdx.x & 63, ty = threadIdx.x >> 6;
#pragma unroll
  for (int i = 0; i < 16; ++i) {
    int r = ty + (i << 2);
    float v = in[(long)(r0 + r) * C + c0 + tx];
    tile[r][tx] = fminf(fmaxf(rintf(v * scale), -128.f), 127.f);
  }
  __syncthreads();
#pragma unroll
  for (int i = 0; i < 16; ++i) {
    int c = ty + (i << 2);
    out[(long)(c0 + c) * R + r0 + tx] = __float2bfloat16(tile[tx][c]);
  }
}

// ---------------- gather-attention: one block per (b,t) ------------------------------------
__global__ __launch_bounds__(256) void attn_kernel(const float* __restrict__ x,
                                                   const int* __restrict__ idx,
                                                   const float* __restrict__ KqT,
                                                   const float* __restrict__ VqT,
                                                   bf16* __restrict__ combHi) {
  int bt = blockIdx.x;
  const float* xr = x + (long)bt * D_MODEL;
  __shared__ int sidx[S_TOP];
  __shared__ float sred[S_TOP][4];
  __shared__ float sp[S_TOP];
  int t = threadIdx.x, lane = t & 63, wid = t >> 6;
  if (t < S_TOP) sidx[t] = idx[(long)bt * S_TOP + t];
  __syncthreads();
  float xv[8];
#pragma unroll
  for (int j = 0; j < 8; ++j) xv[j] = xr[t + (j << 8)];
#pragma unroll
  for (int s = 0; s < S_TOP; ++s) {
    const float* kc = KqT + (long)sidx[s] * D_MODEL;
    float a = 0.f;
#pragma unroll
    for (int j = 0; j < 8; ++j) a += xv[j] * kc[t + (j << 8)];
#pragma unroll
    for (int o = 32; o; o >>= 1) a += __shfl_down(a, o, 64);
    if (lane == 0) sred[s][wid] = a;
  }
  __syncthreads();
  if (t < S_TOP) {
    float sc = sred[t][0] + sred[t][1] + sred[t][2] + sred[t][3];
    float mx = sc;
#pragma unroll
    for (int o = 8; o; o >>= 1) mx = fmaxf(mx, __shfl_xor(mx, o, 16));
    float e = __expf(sc - mx);
    float su = e;
#pragma unroll
    for (int o = 8; o; o >>= 1) su += __shfl_xor(su, o, 16);
    sp[t] = e / su;
  }
  __syncthreads();
  float p[S_TOP];
#pragma unroll
  for (int s = 0; s < S_TOP; ++s) p[s] = sp[s];
#pragma unroll
  for (int j = 0; j < 8; ++j) {
    int d = t + (j << 8);
    float c = 0.f;
#pragma unroll
    for (int s = 0; s < S_TOP; ++s) c += p[s] * VqT[(long)sidx[s] * D_MODEL + d];
    combHi[(long)bt * D_MODEL + d] = __float2bfloat16(c);
  }
}

// ---------------- 256x256 8-wave deep-pipelined GEMM ---------------------------------------
// C[M][N] = A @ B^T * (max/127).  A: [M][KT] bf16 acts, B: [N][KT] bf16 integer codes.
// BK=64, 2 LDS K-tile buffers (ping-pong), 4 phases/K-tile:
//   { vmcnt(2); s_barrier; ds_read frags; issue 1 half-tile prefetch -> dead buffer;
//     setprio(1); 16 MFMA; setprio(0) }  + one end-of-iteration barrier.
// LDS XOR-swizzle (col_byte ^= ((row&4)<<3)|((row&8)<<1)) via pre-swizzled GLOBAL source
// (linear gload_lds dest) + swizzled ds_read addr -> 16-way -> 4-way bank conflict.
// SPLITK: gridDim.z=2, halves atomicAdd f32 into zeroed out (2 addends -> deterministic).
template <int KT, bool SPLITK, typename OutT>
__global__ __launch_bounds__(512, 2) void gemm8(const bf16* __restrict__ A,
                                                const bf16* __restrict__ B,
                                                const unsigned* maxbits,
                                                OutT* __restrict__ out, int Ntot) {
  __shared__ char lds[131072];  // A: [2][256][64] @0 (64KB), B: same @65536
  const int t = threadIdx.x, lane = t & 63, wid = t >> 6;
  const int wr = wid >> 2, wc = wid & 3;            // wave grid 2M x 4N
  // bijective XCD swizzle over (x,y); nwg % 8 == 0 for all our grids
  const int gx = gridDim.x, nwg = gx * gridDim.y;
  const int bid = blockIdx.y * gx + blockIdx.x;
  const int swz = (bid & 7) * (nwg >> 3) + (bid >> 3);
  const long m0 = (long)(swz / gx) << 8;
  const long n0 = (long)(swz % gx) << 8;
  const int NT = (SPLITK ? KT / 2 : KT) / 64;
  const bf16* gA = A + m0 * KT + (SPLITK ? blockIdx.z * (KT / 2) : 0);
  const bf16* gB = B + n0 * KT + (SPLITK ? blockIdx.z * (KT / 2) : 0);

  // staging: thread t covers half-tile linear bytes (r*512+t)*16, r=0,1
  const int xs = (t & 32) | ((t & 64) >> 2);        // row-bit2->bit5, row-bit3->bit4 xor
  const int srow = t >> 3;                          // 0..63 per round
  const int gcol = (((t & 7) << 4) ^ xs) >> 1;      // pre-swizzled source col (elements)
  // frag reads
  const int xr = ((lane & 4) << 3) | ((lane & 8) << 1);
  const int arow = lane & 15;
  const int kcolb = (lane >> 4) << 4;               // 0,16,32,48 bytes

  f32x4 acc[8][4] = {};

#define STAGE(mat, h, j, c)                                                          \
  {                                                                                  \
    const bf16* _g = (mat ? gB : gA) + (long)((h)*128) * KT + (long)(j)*64 + gcol;   \
    char* _l = lds + (mat)*65536 + (c)*32768 + (h)*16384;                            \
    gload16(_g + (long)srow * KT, _l + (t << 4));                                    \
    gload16(_g + (long)(64 + srow) * KT, _l + 8192 + (t << 4));                      \
  }

  // prologue: tile 0 -> buf 0 (A0, A1, B0, B1)
  STAGE(0, 0, 0, 0) STAGE(0, 1, 0, 0) STAGE(1, 0, 0, 0) STAGE(1, 1, 0, 0)

  bf16x8 aF[4][2], bF[4][2];

  for (int j = 0; j < NT; ++j) {
    const int c = j & 1;
    const char* lA = lds + c * 32768;
    const char* lB = lds + 65536 + c * 32768;
    // ---- phase 1: A[m0..3] + B[n0..1], stage next A-half0
    asm volatile("s_waitcnt vmcnt(2)" ::: "memory");  // tile j A0,A1,B0 landed
    __builtin_amdgcn_s_barrier();
#pragma unroll
    for (int m = 0; m < 4; ++m)
#pragma unroll
      for (int ks = 0; ks < 2; ++ks)
        aF[m][ks] = *(const bf16x8*)(lA + (wr * 128 + m * 16 + arow) * 128 +
                                     ((ks * 64 + kcolb) ^ xr));
#pragma unroll
    for (int n = 0; n < 2; ++n)
#pragma unroll
      for (int ks = 0; ks < 2; ++ks)
        bF[n][ks] = *(const bf16x8*)(lB + (wc * 64 + n * 16 + arow) * 128 +
                                     ((ks * 64 + kcolb) ^ xr));
    if (j + 1 < NT) STAGE(0, 0, j + 1, c ^ 1)
    __builtin_amdgcn_s_setprio(1);
#pragma unroll
    for (int m = 0; m < 4; ++m)
#pragma unroll
      for (int n = 0; n < 2; ++n)
#pragma unroll
        for (int ks = 0; ks < 2; ++ks)
          acc[m][n] = __builtin_amdgcn_mfma_f32_16x16x32_bf16(aF[m][ks], bF[n][ks], acc[m][n], 0, 0, 0);
    __builtin_amdgcn_s_setprio(0);
    // ---- phase 2: B[n2..3], stage next A-half1
    if (j + 1 < NT) { asm volatile("s_waitcnt vmcnt(2)" ::: "memory"); }  // tile j B1 landed
    else           { asm volatile("s_waitcnt vmcnt(0)" ::: "memory"); }
    __builtin_amdgcn_s_barrier();
#pragma unroll
    for (int n = 0; n < 2; ++n)
#pragma unroll
      for (int ks = 0; ks < 2; ++ks)
        bF[2 + n][ks] = *(const bf16x8*)(lB + (wc * 64 + (2 + n) * 16 + arow) * 128 +
                                         ((ks * 64 + kcolb) ^ xr));
    if (j + 1 < NT) STAGE(0, 1, j + 1, c ^ 1)
    __builtin_amdgcn_s_setprio(1);
#pragma unroll
    for (int m = 0; m < 4; ++m)
#pragma unroll
      for (int n = 0; n < 2; ++n)
#pragma unroll
        for (int ks = 0; ks < 2; ++ks)
          acc[m][2 + n] = __builtin_amdgcn_mfma_f32_16x16x32_bf16(aF[m][ks], bF[2 + n][ks], acc[m][2 + n], 0, 0, 0);
    __builtin_amdgcn_s_setprio(0);
    // ---- phase 3: A[m4..7] (landed+visible since phase 1), stage next B-half0
#pragma unroll
    for (int m = 0; m < 4; ++m)
#pragma unroll
      for (int ks = 0; ks < 2; ++ks)
        aF[m][ks] = *(const bf16x8*)(lA + (wr * 128 + (4 + m) * 16 + arow) * 128 +
                                     ((ks * 64 + kcolb) ^ xr));
    if (j + 1 < NT) STAGE(1, 0, j + 1, c ^ 1)
    __builtin_amdgcn_s_setprio(1);
#pragma unroll
    for (int m = 0; m < 4; ++m)
#pragma unroll
      for (int n = 0; n < 2; ++n)
#pragma unroll
        for (int ks = 0; ks < 2; ++ks)
          acc[4 + m][n] = __builtin_amdgcn_mfma_f32_16x16x32_bf16(aF[m][ks], bF[n][ks], acc[4 + m][n], 0, 0, 0);
    __builtin_amdgcn_s_setprio(0);
    // ---- phase 4: all frags resident, stage next B-half1
    if (j + 1 < NT) STAGE(1, 1, j + 1, c ^ 1)
    __builtin_amdgcn_s_setprio(1);
#pragma unroll
    for (int m = 0; m < 4; ++m)
#pragma unroll
      for (int n = 0; n < 2; ++n)
#pragma unroll
        for (int ks = 0; ks < 2; ++ks)
          acc[4 + m][2 + n] = __builtin_amdgcn_mfma_f32_16x16x32_bf16(aF[m][ks], bF[2 + n][ks], acc[4 + m][2 + n], 0, 0, 0);
    __builtin_amdgcn_s_setprio(0);
    __builtin_amdgcn_s_barrier();  // all buf-c reads done before next iter stages into it
  }
#undef STAGE

  // volatile AFTER the loop: keeps this VMEM op out of the counted-vmcnt region
  float inv = fmaxf(__uint_as_float(*(volatile const unsigned*)maxbits), 1e-8f) * (1.f / 127.f);
#pragma unroll
  for (int m = 0; m < 8; ++m)
#pragma unroll
    for (int n = 0; n < 4; ++n)
#pragma unroll
      for (int r = 0; r < 4; ++r) {
        long row = m0 + wr * 128 + m * 16 + ((lane >> 4) << 2) + r;  // C/D: row=(lane>>4)*4+reg
        long col = n0 + wc * 64 + n * 16 + (lane & 15);              //      col=lane&15
        float h = acc[m][n][r] * inv;
        if constexpr (SPLITK)
          atomicAdd(&out[row * Ntot + col], h);
        else if constexpr (__is_same(OutT, float))
          out[row * Ntot + col] = h;
        else
          out[row * Ntot + col] = __float2bfloat16(h);
      }
}

extern "C" void kernel_launch(void* const* d_in, const int* in_sizes, int n_in, void* d_out,
                              int out_size, void* d_ws, size_t ws_size, hipStream_t stream) {
  const float* x = (const float*)d_in[0];
  const int* idx = (const int*)d_in[1];
  const float* W_K = (const float*)d_in[2];
  const float* W_V = (const float*)d_in[3];
  const float* W_in = (const float*)d_in[4];
  const float* W_out = (const float*)d_in[5];
  float* out = (float*)d_out;  // reference output dtype is float32

  char* ws = (char*)d_ws;
  size_t off = 0;
  unsigned* maxb = (unsigned*)(ws + off); off += 256;
  float* KqT = (float*)(ws + off); off += (size_t)N_KV * D_MODEL * 4;   // [256][2048] f32
  float* VqT = (float*)(ws + off); off += (size_t)N_KV * D_MODEL * 4;
  bf16* QinT = (bf16*)(ws + off); off += (size_t)D_FF * D_MODEL * 2;    // [8192][2048]
  // comb region; QoutT overlays it after GEMM1 (comb dead by then)
  bf16* combHi = (bf16*)(ws + off);
  bf16* QoutT = (bf16*)(ws + off);
  off += (size_t)D_MODEL * D_FF * 2;  // 33.5 MB ([2048][8192])
  bf16* hidHi = (bf16*)(ws + off); off += (size_t)M_ROWS * D_FF * 2;    // 67 MB

  hipMemsetAsync(maxb, 0, 16, stream);
  hipMemsetAsync(out, 0, (size_t)M_ROWS * D_MODEL * 4, stream);  // split-K atomic target
  maxabs_kernel<<<512, 256, 0, stream>>>((const float4*)W_K, (D_MODEL * N_KV) / 4, maxb + 0);
  maxabs_kernel<<<512, 256, 0, stream>>>((const float4*)W_V, (D_MODEL * N_KV) / 4, maxb + 1);
  maxabs_kernel<<<1024, 256, 0, stream>>>((const float4*)W_in, (D_MODEL * D_FF) / 4, maxb + 2);
  maxabs_kernel<<<1024, 256, 0, stream>>>((const float4*)W_out, (D_FF * D_MODEL) / 4, maxb + 3);

  quantT_f32<<<dim3(N_KV / 64, D_MODEL / 64), 256, 0, stream>>>(W_K, KqT, D_MODEL, N_KV, maxb + 0);
  quantT_f32<<<dim3(N_KV / 64, D_MODEL / 64), 256, 0, stream>>>(W_V, VqT, D_MODEL, N_KV, maxb + 1);
  quantT_bf16<<<dim3(D_FF / 64, D_MODEL / 64), 256, 0, stream>>>(W_in, QinT, D_MODEL, D_FF, maxb + 2);

  attn_kernel<<<M_ROWS, 256, 0, stream>>>(x, idx, KqT, VqT, combHi);

  gemm8<D_MODEL, false, bf16><<<dim3(D_FF / 256, M_ROWS / 256), 512, 0, stream>>>(
      combHi, QinT, maxb + 2, hidHi, D_FF);

  quantT_bf16<<<dim3(D_MODEL / 64, D_FF / 64), 256, 0, stream>>>(W_out, QoutT, D_FF, D_MODEL, maxb + 3);

  gemm8<D_FF, true, float><<<dim3(D_MODEL / 256, M_ROWS / 256, 2), 512, 0, stream>>>(
      hidHi, QoutT, maxb + 3, out, D_MODEL);
}

// Round 5
// 476.945 us; speedup vs baseline: 1.6602x; 1.0935x over previous
//
#include <hip/hip_runtime.h>
#include <hip/hip_bf16.h>

// Problem constants
#define D_MODEL 2048
#define D_FF    8192
#define N_KV    256
#define S_TOP   16
#define M_ROWS  4096   // B*T = 4*1024

typedef __attribute__((ext_vector_type(8))) short bf16x8;   // 8 bf16 (4 VGPRs)
typedef __attribute__((ext_vector_type(4))) float f32x4;
typedef __hip_bfloat16 bf16;

typedef const __attribute__((address_space(1))) unsigned int* gp_t;
typedef __attribute__((address_space(3))) unsigned int* lp_t;

__device__ __forceinline__ void gload16(const void* g, void* l) {
  // async global->LDS, 16B per lane; LDS dest = wave-uniform base + lane*16
  __builtin_amdgcn_global_load_lds((gp_t)g, (lp_t)l, 16, 0, 0);
}

// ---------------- max|w| reduction (atomicMax on float bits; bits monotone for w>=0) -------
__global__ __launch_bounds__(256) void maxabs_kernel(const float4* __restrict__ w, int n4,
                                                     unsigned* __restrict__ out) {
  float m = 0.f;
  for (long i = (long)blockIdx.x * 256 + threadIdx.x; i < n4; i += (long)gridDim.x * 256) {
    float4 v = w[i];
    m = fmaxf(m, fmaxf(fmaxf(fabsf(v.x), fabsf(v.y)), fmaxf(fabsf(v.z), fabsf(v.w))));
  }
#pragma unroll
  for (int o = 32; o; o >>= 1) m = fmaxf(m, __shfl_down(m, o, 64));
  __shared__ float sm[4];
  int lane = threadIdx.x & 63, wid = threadIdx.x >> 6;
  if (lane == 0) sm[wid] = m;
  __syncthreads();
  if (threadIdx.x == 0) {
    float mm = fmaxf(fmaxf(sm[0], sm[1]), fmaxf(sm[2], sm[3]));
    atomicMax(out, __float_as_uint(mm));
  }
}

// ---------------- quantize + transpose: in [R][C] f32 -> out [C][R] ------------------------
__global__ __launch_bounds__(256) void quantT_f32(const float* __restrict__ in,
                                                  float* __restrict__ out, int R, int C,
                                                  const unsigned* __restrict__ maxbits) {
  __shared__ float tile[64][65];
  float scale = 127.f / fmaxf(__uint_as_float(*maxbits), 1e-8f);
  int r0 = blockIdx.y << 6, c0 = blockIdx.x << 6;
  int tx = threadIdx.x & 63, ty = threadIdx.x >> 6;
#pragma unroll
  for (int i = 0; i < 16; ++i) {
    int r = ty + (i << 2);
    float v = in[(long)(r0 + r) * C + c0 + tx];
    tile[r][tx] = fminf(fmaxf(rintf(v * scale), -128.f), 127.f);
  }
  __syncthreads();
#pragma unroll
  for (int i = 0; i < 16; ++i) {
    int c = ty + (i << 2);
    out[(long)(c0 + c) * R + r0 + tx] = tile[tx][c] / scale;
  }
}

// bf16 variant stores the INTEGER code (exact in bf16, |q|<=128); scale folded into epilogue.
__global__ __launch_bounds__(256) void quantT_bf16(const float* __restrict__ in,
                                                   bf16* __restrict__ out, int R, int C,
                                                   const unsigned* __restrict__ maxbits) {
  __shared__ float tile[64][65];
  float scale = 127.f / fmaxf(__uint_as_float(*maxbits), 1e-8f);
  int r0 = blockIdx.y << 6, c0 = blockIdx.x << 6;
  int tx = threadIdx.x & 63, ty = threadIdx.x >> 6;
#pragma unroll
  for (int i = 0; i < 16; ++i) {
    int r = ty + (i << 2);
    float v = in[(long)(r0 + r) * C + c0 + tx];
    tile[r][tx] = fminf(fmaxf(rintf(v * scale), -128.f), 127.f);
  }
  __syncthreads();
#pragma unroll
  for (int i = 0; i < 16; ++i) {
    int c = ty + (i << 2);
    out[(long)(c0 + c) * R + r0 + tx] = __float2bfloat16(tile[tx][c]);
  }
}

// ---------------- gather-attention: one block per (b,t) ------------------------------------
__global__ __launch_bounds__(256) void attn_kernel(const float* __restrict__ x,
                                                   const int* __restrict__ idx,
                                                   const float* __restrict__ KqT,
                                                   const float* __restrict__ VqT,
                                                   bf16* __restrict__ combHi) {
  int bt = blockIdx.x;
  const float* xr = x + (long)bt * D_MODEL;
  __shared__ int sidx[S_TOP];
  __shared__ float sred[S_TOP][4];
  __shared__ float sp[S_TOP];
  int t = threadIdx.x, lane = t & 63, wid = t >> 6;
  if (t < S_TOP) sidx[t] = idx[(long)bt * S_TOP + t];
  __syncthreads();
  float xv[8];
#pragma unroll
  for (int j = 0; j < 8; ++j) xv[j] = xr[t + (j << 8)];
#pragma unroll
  for (int s = 0; s < S_TOP; ++s) {
    const float* kc = KqT + (long)sidx[s] * D_MODEL;
    float a = 0.f;
#pragma unroll
    for (int j = 0; j < 8; ++j) a += xv[j] * kc[t + (j << 8)];
#pragma unroll
    for (int o = 32; o; o >>= 1) a += __shfl_down(a, o, 64);
    if (lane == 0) sred[s][wid] = a;
  }
  __syncthreads();
  if (t < S_TOP) {
    float sc = sred[t][0] + sred[t][1] + sred[t][2] + sred[t][3];
    float mx = sc;
#pragma unroll
    for (int o = 8; o; o >>= 1) mx = fmaxf(mx, __shfl_xor(mx, o, 16));
    float e = __expf(sc - mx);
    float su = e;
#pragma unroll
    for (int o = 8; o; o >>= 1) su += __shfl_xor(su, o, 16);
    sp[t] = e / su;
  }
  __syncthreads();
  float p[S_TOP];
#pragma unroll
  for (int s = 0; s < S_TOP; ++s) p[s] = sp[s];
#pragma unroll
  for (int j = 0; j < 8; ++j) {
    int d = t + (j << 8);
    float c = 0.f;
#pragma unroll
    for (int s = 0; s < S_TOP; ++s) c += p[s] * VqT[(long)sidx[s] * D_MODEL + d];
    combHi[(long)bt * D_MODEL + d] = __float2bfloat16(c);
  }
}

// ---------------- 256x256 8-wave deep-pipelined GEMM ---------------------------------------
// C[M][N] = A @ B^T * (max/127).  A: [M][KT] bf16 acts, B: [N][KT] bf16 integer codes.
// BK=64, ping-pong LDS K-tile buffers. Per iteration (one K-tile):
//   vmcnt(0)+s_barrier  (tile j fully landed, block-wide: own-drain + barrier symmetry)
//   phase1: ds aF[m0-3],bF[n0-1]; stage A0',A1'; 16 MFMA
//   phase2: ds bF[n2-3];          stage B0',B1'; 16 MFMA
//   s_barrier (lockstep)
//   phase3: ds aF[m4-7];                          16 MFMA
//   phase4:                                       16 MFMA
// All of tile j+1 is issued by end of phase 2 -> ~2.5 phases of latency cover at next wait.
// LDS bank swizzle: byte_col ^= (row&7)<<4 (bits 4,5,6) -- spreads a frag-read's 16 rows
// across all 8 16B-slots/32 banks (8 lanes/slot = b128 floor). Applied as linear gload_lds
// dest + inverse-swizzled GLOBAL source col + swizzled ds_read addr (both-sides rule).
// SPLITK: gridDim.z=2, halves atomicAdd f32 into zeroed out (2 addends -> deterministic).
template <int KT, bool SPLITK, typename OutT>
__global__ __launch_bounds__(512, 2) void gemm8(const bf16* __restrict__ A,
                                                const bf16* __restrict__ B,
                                                const unsigned* maxbits,
                                                OutT* __restrict__ out, int Ntot) {
  __shared__ char lds[131072];  // A: [2][256][64] @0 (64KB), B: same @65536
  const int t = threadIdx.x, lane = t & 63, wid = t >> 6;
  const int wr = wid >> 2, wc = wid & 3;            // wave grid 2M x 4N
  // bijective XCD swizzle over (x,y); nwg % 8 == 0 for all our grids
  const int gx = gridDim.x, nwg = gx * gridDim.y;
  const int bid = blockIdx.y * gx + blockIdx.x;
  const int swz = (bid & 7) * (nwg >> 3) + (bid >> 3);
  const long m0 = (long)(swz / gx) << 8;
  const long n0 = (long)(swz % gx) << 8;
  const int NT = (SPLITK ? KT / 2 : KT) / 64;
  const bf16* gA = A + m0 * KT + (SPLITK ? blockIdx.z * (KT / 2) : 0);
  const bf16* gB = B + n0 * KT + (SPLITK ? blockIdx.z * (KT / 2) : 0);

  // staging: thread t covers row srow=t>>3, 16B slot (t&7); source col inverse-swizzled
  const int srow = t >> 3;                           // 0..63 per gload round
  const int gcol = ((t & 7) ^ (srow & 7)) << 3;      // elements (bytes>>1)
  // frag reads: byte col ^= (row&7)<<4; row&7 == lane&7 (all row bases are mult of 16)
  const int xr = (lane & 7) << 4;
  const int arow = lane & 15;
  const int kcolb = (lane >> 4) << 4;                // 0,16,32,48 bytes

  f32x4 acc[8][4] = {};

#define STAGE(mat, h, j, c)                                                          \
  {                                                                                  \
    const bf16* _g = (mat ? gB : gA) + (long)((h)*128) * KT + (long)(j)*64 + gcol;   \
    char* _l = lds + (mat)*65536 + (c)*32768 + (h)*16384;                            \
    gload16(_g + (long)srow * KT, _l + (t << 4));                                    \
    gload16(_g + (long)(64 + srow) * KT, _l + 8192 + (t << 4));                      \
  }

  // prologue: tile 0 -> buf 0 (A0, A1, B0, B1)
  STAGE(0, 0, 0, 0) STAGE(0, 1, 0, 0) STAGE(1, 0, 0, 0) STAGE(1, 1, 0, 0)

  bf16x8 aF[4][2], bF[4][2];

  for (int j = 0; j < NT; ++j) {
    const int c = j & 1;
    const char* lA = lds + c * 32768;
    const char* lB = lds + 65536 + c * 32768;
    asm volatile("s_waitcnt vmcnt(0)" ::: "memory");  // tile j fully landed (own loads)
    __builtin_amdgcn_s_barrier();                     // -> all waves' loads landed
    // ---- phase 1: A[m0..3] + B[n0..1]; stage next A
#pragma unroll
    for (int m = 0; m < 4; ++m)
#pragma unroll
      for (int ks = 0; ks < 2; ++ks)
        aF[m][ks] = *(const bf16x8*)(lA + (wr * 128 + m * 16 + arow) * 128 +
                                     ((ks * 64 + kcolb) ^ xr));
#pragma unroll
    for (int n = 0; n < 2; ++n)
#pragma unroll
      for (int ks = 0; ks < 2; ++ks)
        bF[n][ks] = *(const bf16x8*)(lB + (wc * 64 + n * 16 + arow) * 128 +
                                     ((ks * 64 + kcolb) ^ xr));
    if (j + 1 < NT) { STAGE(0, 0, j + 1, c ^ 1) STAGE(0, 1, j + 1, c ^ 1) }
    __builtin_amdgcn_s_setprio(1);
#pragma unroll
    for (int m = 0; m < 4; ++m)
#pragma unroll
      for (int n = 0; n < 2; ++n)
#pragma unroll
        for (int ks = 0; ks < 2; ++ks)
          acc[m][n] = __builtin_amdgcn_mfma_f32_16x16x32_bf16(aF[m][ks], bF[n][ks], acc[m][n], 0, 0, 0);
    __builtin_amdgcn_s_setprio(0);
    // ---- phase 2: B[n2..3]; stage next B
#pragma unroll
    for (int n = 0; n < 2; ++n)
#pragma unroll
      for (int ks = 0; ks < 2; ++ks)
        bF[2 + n][ks] = *(const bf16x8*)(lB + (wc * 64 + (2 + n) * 16 + arow) * 128 +
                                         ((ks * 64 + kcolb) ^ xr));
    if (j + 1 < NT) { STAGE(1, 0, j + 1, c ^ 1) STAGE(1, 1, j + 1, c ^ 1) }
    __builtin_amdgcn_s_setprio(1);
#pragma unroll
    for (int m = 0; m < 4; ++m)
#pragma unroll
      for (int n = 0; n < 2; ++n)
#pragma unroll
        for (int ks = 0; ks < 2; ++ks)
          acc[m][2 + n] = __builtin_amdgcn_mfma_f32_16x16x32_bf16(aF[m][ks], bF[2 + n][ks], acc[m][2 + n], 0, 0, 0);
    __builtin_amdgcn_s_setprio(0);
    __builtin_amdgcn_s_barrier();  // lockstep; keeps phase structure from collapsing
    // ---- phase 3: A[m4..7]
#pragma unroll
    for (int m = 0; m < 4; ++m)
#pragma unroll
      for (int ks = 0; ks < 2; ++ks)
        aF[m][ks] = *(const bf16x8*)(lA + (wr * 128 + (4 + m) * 16 + arow) * 128 +
                                     ((ks * 64 + kcolb) ^ xr));
    __builtin_amdgcn_s_setprio(1);
#pragma unroll
    for (int m = 0; m < 4; ++m)
#pragma unroll
      for (int n = 0; n < 2; ++n)
#pragma unroll
        for (int ks = 0; ks < 2; ++ks)
          acc[4 + m][n] = __builtin_amdgcn_mfma_f32_16x16x32_bf16(aF[m][ks], bF[n][ks], acc[4 + m][n], 0, 0, 0);
    __builtin_amdgcn_s_setprio(0);
    // ---- phase 4
    __builtin_amdgcn_s_setprio(1);
#pragma unroll
    for (int m = 0; m < 4; ++m)
#pragma unroll
      for (int n = 0; n < 2; ++n)
#pragma unroll
        for (int ks = 0; ks < 2; ++ks)
          acc[4 + m][2 + n] = __builtin_amdgcn_mfma_f32_16x16x32_bf16(aF[m][ks], bF[2 + n][ks], acc[4 + m][2 + n], 0, 0, 0);
    __builtin_amdgcn_s_setprio(0);
  }
#undef STAGE

  // volatile AFTER the loop: keeps this VMEM op out of the pipelined region
  float inv = fmaxf(__uint_as_float(*(volatile const unsigned*)maxbits), 1e-8f) * (1.f / 127.f);
#pragma unroll
  for (int m = 0; m < 8; ++m)
#pragma unroll
    for (int n = 0; n < 4; ++n)
#pragma unroll
      for (int r = 0; r < 4; ++r) {
        long row = m0 + wr * 128 + m * 16 + ((lane >> 4) << 2) + r;  // C/D: row=(lane>>4)*4+reg
        long col = n0 + wc * 64 + n * 16 + (lane & 15);              //      col=lane&15
        float h = acc[m][n][r] * inv;
        if constexpr (SPLITK)
          atomicAdd(&out[row * Ntot + col], h);
        else if constexpr (__is_same(OutT, float))
          out[row * Ntot + col] = h;
        else
          out[row * Ntot + col] = __float2bfloat16(h);
      }
}

extern "C" void kernel_launch(void* const* d_in, const int* in_sizes, int n_in, void* d_out,
                              int out_size, void* d_ws, size_t ws_size, hipStream_t stream) {
  const float* x = (const float*)d_in[0];
  const int* idx = (const int*)d_in[1];
  const float* W_K = (const float*)d_in[2];
  const float* W_V = (const float*)d_in[3];
  const float* W_in = (const float*)d_in[4];
  const float* W_out = (const float*)d_in[5];
  float* out = (float*)d_out;  // reference output dtype is float32

  char* ws = (char*)d_ws;
  size_t off = 0;
  unsigned* maxb = (unsigned*)(ws + off); off += 256;
  float* KqT = (float*)(ws + off); off += (size_t)N_KV * D_MODEL * 4;   // [256][2048] f32
  float* VqT = (float*)(ws + off); off += (size_t)N_KV * D_MODEL * 4;
  bf16* QinT = (bf16*)(ws + off); off += (size_t)D_FF * D_MODEL * 2;    // [8192][2048]
  // comb region; QoutT overlays it after GEMM1 (comb dead by then)
  bf16* combHi = (bf16*)(ws + off);
  bf16* QoutT = (bf16*)(ws + off);
  off += (size_t)D_MODEL * D_FF * 2;  // 33.5 MB ([2048][8192])
  bf16* hidHi = (bf16*)(ws + off); off += (size_t)M_ROWS * D_FF * 2;    // 67 MB

  hipMemsetAsync(maxb, 0, 16, stream);
  hipMemsetAsync(out, 0, (size_t)M_ROWS * D_MODEL * 4, stream);  // split-K atomic target
  maxabs_kernel<<<512, 256, 0, stream>>>((const float4*)W_K, (D_MODEL * N_KV) / 4, maxb + 0);
  maxabs_kernel<<<512, 256, 0, stream>>>((const float4*)W_V, (D_MODEL * N_KV) / 4, maxb + 1);
  maxabs_kernel<<<1024, 256, 0, stream>>>((const float4*)W_in, (D_MODEL * D_FF) / 4, maxb + 2);
  maxabs_kernel<<<1024, 256, 0, stream>>>((const float4*)W_out, (D_FF * D_MODEL) / 4, maxb + 3);

  quantT_f32<<<dim3(N_KV / 64, D_MODEL / 64), 256, 0, stream>>>(W_K, KqT, D_MODEL, N_KV, maxb + 0);
  quantT_f32<<<dim3(N_KV / 64, D_MODEL / 64), 256, 0, stream>>>(W_V, VqT, D_MODEL, N_KV, maxb + 1);
  quantT_bf16<<<dim3(D_FF / 64, D_MODEL / 64), 256, 0, stream>>>(W_in, QinT, D_MODEL, D_FF, maxb + 2);

  attn_kernel<<<M_ROWS, 256, 0, stream>>>(x, idx, KqT, VqT, combHi);

  gemm8<D_MODEL, false, bf16><<<dim3(D_FF / 256, M_ROWS / 256), 512, 0, stream>>>(
      combHi, QinT, maxb + 2, hidHi, D_FF);

  quantT_bf16<<<dim3(D_MODEL / 64, D_FF / 64), 256, 0, stream>>>(W_out, QoutT, D_FF, D_MODEL, maxb + 3);

  gemm8<D_FF, true, float><<<dim3(D_MODEL / 256, M_ROWS / 256, 2), 512, 0, stream>>>(
      hidHi, QoutT, maxb + 3, out, D_MODEL);
}

// Round 6
// 452.851 us; speedup vs baseline: 1.7485x; 1.0532x over previous
//
#include <hip/hip_runtime.h>
#include <hip/hip_bf16.h>

// Problem constants
#define D_MODEL 2048
#define D_FF    8192
#define N_KV    256
#define S_TOP   16
#define M_ROWS  4096   // B*T = 4*1024

typedef __attribute__((ext_vector_type(8))) short bf16x8;   // 8 bf16 (4 VGPRs)
typedef __attribute__((ext_vector_type(4))) float f32x4;
typedef __hip_bfloat16 bf16;

typedef const __attribute__((address_space(1))) unsigned int* gp_t;
typedef __attribute__((address_space(3))) unsigned int* lp_t;

__device__ __forceinline__ void gload16(const void* g, void* l) {
  // async global->LDS, 16B per lane; LDS dest = wave-uniform base + lane*16
  __builtin_amdgcn_global_load_lds((gp_t)g, (lp_t)l, 16, 0, 0);
}

// ---------------- fused max|w| over the 4 weight tensors (blockIdx.y selects tensor) -------
__global__ __launch_bounds__(256) void maxabs4_kernel(const float4* __restrict__ w0, int n0,
                                                      const float4* __restrict__ w1, int n1,
                                                      const float4* __restrict__ w2, int n2,
                                                      const float4* __restrict__ w3, int n3,
                                                      unsigned* __restrict__ out) {
  const float4* w = blockIdx.y == 0 ? w0 : blockIdx.y == 1 ? w1 : blockIdx.y == 2 ? w2 : w3;
  int n4 = blockIdx.y == 0 ? n0 : blockIdx.y == 1 ? n1 : blockIdx.y == 2 ? n2 : n3;
  float m = 0.f;
  for (long i = (long)blockIdx.x * 256 + threadIdx.x; i < n4; i += (long)gridDim.x * 256) {
    float4 v = w[i];
    m = fmaxf(m, fmaxf(fmaxf(fabsf(v.x), fabsf(v.y)), fmaxf(fabsf(v.z), fabsf(v.w))));
  }
#pragma unroll
  for (int o = 32; o; o >>= 1) m = fmaxf(m, __shfl_down(m, o, 64));
  __shared__ float sm[4];
  int lane = threadIdx.x & 63, wid = threadIdx.x >> 6;
  if (lane == 0) sm[wid] = m;
  __syncthreads();
  if (threadIdx.x == 0) {
    float mm = fmaxf(fmaxf(sm[0], sm[1]), fmaxf(sm[2], sm[3]));
    atomicMax(out + blockIdx.y, __float_as_uint(mm));
  }
}

// ---------------- quantize + transpose: in [R][C] f32 -> out [C][R] ------------------------
__global__ __launch_bounds__(256) void quantT_f32(const float* __restrict__ in,
                                                  float* __restrict__ out, int R, int C,
                                                  const unsigned* __restrict__ maxbits) {
  __shared__ float tile[64][65];
  float scale = 127.f / fmaxf(__uint_as_float(*maxbits), 1e-8f);
  int r0 = blockIdx.y << 6, c0 = blockIdx.x << 6;
  int tx = threadIdx.x & 63, ty = threadIdx.x >> 6;
#pragma unroll
  for (int i = 0; i < 16; ++i) {
    int r = ty + (i << 2);
    float v = in[(long)(r0 + r) * C + c0 + tx];
    tile[r][tx] = fminf(fmaxf(rintf(v * scale), -128.f), 127.f);
  }
  __syncthreads();
#pragma unroll
  for (int i = 0; i < 16; ++i) {
    int c = ty + (i << 2);
    out[(long)(c0 + c) * R + r0 + tx] = tile[tx][c] / scale;
  }
}

// bf16 variant stores the INTEGER code (exact in bf16, |q|<=128); scale folded into epilogue.
__global__ __launch_bounds__(256) void quantT_bf16(const float* __restrict__ in,
                                                   bf16* __restrict__ out, int R, int C,
                                                   const unsigned* __restrict__ maxbits) {
  __shared__ float tile[64][65];
  float scale = 127.f / fmaxf(__uint_as_float(*maxbits), 1e-8f);
  int r0 = blockIdx.y << 6, c0 = blockIdx.x << 6;
  int tx = threadIdx.x & 63, ty = threadIdx.x >> 6;
#pragma unroll
  for (int i = 0; i < 16; ++i) {
    int r = ty + (i << 2);
    float v = in[(long)(r0 + r) * C + c0 + tx];
    tile[r][tx] = fminf(fmaxf(rintf(v * scale), -128.f), 127.f);
  }
  __syncthreads();
#pragma unroll
  for (int i = 0; i < 16; ++i) {
    int c = ty + (i << 2);
    out[(long)(c0 + c) * R + r0 + tx] = __float2bfloat16(tile[tx][c]);
  }
}

// ---------------- gather-attention: one block per (b,t) ------------------------------------
__global__ __launch_bounds__(256) void attn_kernel(const float* __restrict__ x,
                                                   const int* __restrict__ idx,
                                                   const float* __restrict__ KqT,
                                                   const float* __restrict__ VqT,
                                                   bf16* __restrict__ combHi) {
  int bt = blockIdx.x;
  const float* xr = x + (long)bt * D_MODEL;
  __shared__ int sidx[S_TOP];
  __shared__ float sred[S_TOP][4];
  __shared__ float sp[S_TOP];
  int t = threadIdx.x, lane = t & 63, wid = t >> 6;
  if (t < S_TOP) sidx[t] = idx[(long)bt * S_TOP + t];
  __syncthreads();
  float xv[8];
#pragma unroll
  for (int j = 0; j < 8; ++j) xv[j] = xr[t + (j << 8)];
#pragma unroll
  for (int s = 0; s < S_TOP; ++s) {
    const float* kc = KqT + (long)sidx[s] * D_MODEL;
    float a = 0.f;
#pragma unroll
    for (int j = 0; j < 8; ++j) a += xv[j] * kc[t + (j << 8)];
#pragma unroll
    for (int o = 32; o; o >>= 1) a += __shfl_down(a, o, 64);
    if (lane == 0) sred[s][wid] = a;
  }
  __syncthreads();
  if (t < S_TOP) {
    float sc = sred[t][0] + sred[t][1] + sred[t][2] + sred[t][3];
    float mx = sc;
#pragma unroll
    for (int o = 8; o; o >>= 1) mx = fmaxf(mx, __shfl_xor(mx, o, 16));
    float e = __expf(sc - mx);
    float su = e;
#pragma unroll
    for (int o = 8; o; o >>= 1) su += __shfl_xor(su, o, 16);
    sp[t] = e / su;
  }
  __syncthreads();
  float p[S_TOP];
#pragma unroll
  for (int s = 0; s < S_TOP; ++s) p[s] = sp[s];
#pragma unroll
  for (int j = 0; j < 8; ++j) {
    int d = t + (j << 8);
    float c = 0.f;
#pragma unroll
    for (int s = 0; s < S_TOP; ++s) c += p[s] * VqT[(long)sidx[s] * D_MODEL + d];
    combHi[(long)bt * D_MODEL + d] = __float2bfloat16(c);
  }
}

// ---------------- 256x256 8-wave deep-pipelined GEMM (counted-vmcnt schedule) --------------
// C[M][N] = A @ B^T * (max/127).  A: [M][KT] bf16 acts, B: [N][KT] bf16 integer codes.
// BK=64, ping-pong LDS. Staging FIFO per tile (in order): A0,A1 (phase1) B0,B1 (phase2),
// 2 gloads each. Waits are COUNTED (never drain in-loop):
//   top:      vmcnt(2)  -> tile j's A0,A1,B0 landed (B1 may fly);  s_barrier
//   phase1:   ds aF[0-3](A0), bF[0-1](B0); stage A0',A1'; MFMA x16
//   mid:      vmcnt(4) [last iter: 0] -> tile j's B1 landed;       s_barrier
//   phase2:   ds bF[2-3](B1); stage B0',B1'; MFMA x16
//   phase3:   ds aF[4-7](A1); MFMA x16        (A1 covered by top wait)
//   phase4:   MFMA x16
// Oldest-load wait distance ~= 1 full iteration -> latency covered (m218 counted-vmcnt).
// LDS bank swizzle: byte_col ^= (row&7)<<4 via pre-swizzled global source col + swizzled
// ds_read (both-sides rule); measured conflict-free (r5: SQ_LDS_BANK_CONFLICT = 0).
// SPLITK: gridDim.z=2, halves atomicAdd f32 into zeroed out (2 addends -> deterministic).
template <int KT, bool SPLITK, typename OutT>
__global__ __launch_bounds__(512, 2) void gemm8(const bf16* __restrict__ A,
                                                const bf16* __restrict__ B,
                                                const unsigned* maxbits,
                                                OutT* __restrict__ out, int Ntot) {
  __shared__ char lds[131072];  // A: [2][256][64] @0 (64KB), B: same @65536
  const int t = threadIdx.x, lane = t & 63, wid = t >> 6;
  const int wr = wid >> 2, wc = wid & 3;            // wave grid 2M x 4N
  // bijective XCD swizzle over (x,y); nwg % 8 == 0 for all our grids
  const int gx = gridDim.x, nwg = gx * gridDim.y;
  const int bid = blockIdx.y * gx + blockIdx.x;
  const int swz = (bid & 7) * (nwg >> 3) + (bid >> 3);
  const long m0 = (long)(swz / gx) << 8;
  const long n0 = (long)(swz % gx) << 8;
  const int NT = (SPLITK ? KT / 2 : KT) / 64;
  const bf16* gA = A + m0 * KT + (SPLITK ? blockIdx.z * (KT / 2) : 0);
  const bf16* gB = B + n0 * KT + (SPLITK ? blockIdx.z * (KT / 2) : 0);

  // staging: thread t covers row srow=t>>3, 16B slot (t&7); source col inverse-swizzled
  const int srow = t >> 3;                           // 0..63 per gload round
  const int gcol = ((t & 7) ^ (srow & 7)) << 3;      // elements (bytes>>1)
  // frag reads: byte col ^= (row&7)<<4; row&7 == lane&7 (all row bases are mult of 16)
  const int xr = (lane & 7) << 4;
  const int arow = lane & 15;
  const int kcolb = (lane >> 4) << 4;                // 0,16,32,48 bytes

  f32x4 acc[8][4] = {};

#define STAGE(mat, h, j, c)                                                          \
  {                                                                                  \
    const bf16* _g = (mat ? gB : gA) + (long)((h)*128) * KT + (long)(j)*64 + gcol;   \
    char* _l = lds + (mat)*65536 + (c)*32768 + (h)*16384;                            \
    gload16(_g + (long)srow * KT, _l + (t << 4));                                    \
    gload16(_g + (long)(64 + srow) * KT, _l + 8192 + (t << 4));                      \
  }

  // prologue: tile 0 -> buf 0, FIFO order A0,A1,B0,B1
  STAGE(0, 0, 0, 0) STAGE(0, 1, 0, 0) STAGE(1, 0, 0, 0) STAGE(1, 1, 0, 0)

  bf16x8 aF[4][2], bF[4][2];

  for (int j = 0; j < NT; ++j) {
    const int c = j & 1;
    const char* lA = lds + c * 32768;
    const char* lB = lds + 65536 + c * 32768;
    asm volatile("s_waitcnt vmcnt(2)" ::: "memory");  // tile j A0,A1,B0 landed (own loads)
    __builtin_amdgcn_s_barrier();                     // -> block-wide
    // ---- phase 1: A[m0..3] (A0) + B[n0..1] (B0); stage next A
#pragma unroll
    for (int m = 0; m < 4; ++m)
#pragma unroll
      for (int ks = 0; ks < 2; ++ks)
        aF[m][ks] = *(const bf16x8*)(lA + (wr * 128 + m * 16 + arow) * 128 +
                                     ((ks * 64 + kcolb) ^ xr));
#pragma unroll
    for (int n = 0; n < 2; ++n)
#pragma unroll
      for (int ks = 0; ks < 2; ++ks)
        bF[n][ks] = *(const bf16x8*)(lB + (wc * 64 + n * 16 + arow) * 128 +
                                     ((ks * 64 + kcolb) ^ xr));
    if (j + 1 < NT) { STAGE(0, 0, j + 1, c ^ 1) STAGE(0, 1, j + 1, c ^ 1) }
    __builtin_amdgcn_s_setprio(1);
#pragma unroll
    for (int m = 0; m < 4; ++m)
#pragma unroll
      for (int n = 0; n < 2; ++n)
#pragma unroll
        for (int ks = 0; ks < 2; ++ks)
          acc[m][n] = __builtin_amdgcn_mfma_f32_16x16x32_bf16(aF[m][ks], bF[n][ks], acc[m][n], 0, 0, 0);
    __builtin_amdgcn_s_setprio(0);
    // ---- mid wait: tile j's B1 landed (outstanding: B1_j + 4 A'-loads just staged)
    if (j + 1 < NT) { asm volatile("s_waitcnt vmcnt(4)" ::: "memory"); }
    else           { asm volatile("s_waitcnt vmcnt(0)" ::: "memory"); }
    __builtin_amdgcn_s_barrier();
    // ---- phase 2: B[n2..3] (B1); stage next B
#pragma unroll
    for (int n = 0; n < 2; ++n)
#pragma unroll
      for (int ks = 0; ks < 2; ++ks)
        bF[2 + n][ks] = *(const bf16x8*)(lB + (wc * 64 + (2 + n) * 16 + arow) * 128 +
                                         ((ks * 64 + kcolb) ^ xr));
    if (j + 1 < NT) { STAGE(1, 0, j + 1, c ^ 1) STAGE(1, 1, j + 1, c ^ 1) }
    __builtin_amdgcn_s_setprio(1);
#pragma unroll
    for (int m = 0; m < 4; ++m)
#pragma unroll
      for (int n = 0; n < 2; ++n)
#pragma unroll
        for (int ks = 0; ks < 2; ++ks)
          acc[m][2 + n] = __builtin_amdgcn_mfma_f32_16x16x32_bf16(aF[m][ks], bF[2 + n][ks], acc[m][2 + n], 0, 0, 0);
    __builtin_amdgcn_s_setprio(0);
    // ---- phase 3: A[m4..7] (A1; landed per top wait)
#pragma unroll
    for (int m = 0; m < 4; ++m)
#pragma unroll
      for (int ks = 0; ks < 2; ++ks)
        aF[m][ks] = *(const bf16x8*)(lA + (wr * 128 + (4 + m) * 16 + arow) * 128 +
                                     ((ks * 64 + kcolb) ^ xr));
    __builtin_amdgcn_s_setprio(1);
#pragma unroll
    for (int m = 0; m < 4; ++m)
#pragma unroll
      for (int n = 0; n < 2; ++n)
#pragma unroll
        for (int ks = 0; ks < 2; ++ks)
          acc[4 + m][n] = __builtin_amdgcn_mfma_f32_16x16x32_bf16(aF[m][ks], bF[n][ks], acc[4 + m][n], 0, 0, 0);
    __builtin_amdgcn_s_setprio(0);
    // ---- phase 4
    __builtin_amdgcn_s_setprio(1);
#pragma unroll
    for (int m = 0; m < 4; ++m)
#pragma unroll
      for (int n = 0; n < 2; ++n)
#pragma unroll
        for (int ks = 0; ks < 2; ++ks)
          acc[4 + m][2 + n] = __builtin_amdgcn_mfma_f32_16x16x32_bf16(aF[m][ks], bF[2 + n][ks], acc[4 + m][2 + n], 0, 0, 0);
    __builtin_amdgcn_s_setprio(0);
  }
#undef STAGE

  // volatile AFTER the loop: keeps this VMEM op out of the pipelined region
  float inv = fmaxf(__uint_as_float(*(volatile const unsigned*)maxbits), 1e-8f) * (1.f / 127.f);
#pragma unroll
  for (int m = 0; m < 8; ++m)
#pragma unroll
    for (int n = 0; n < 4; ++n)
#pragma unroll
      for (int r = 0; r < 4; ++r) {
        long row = m0 + wr * 128 + m * 16 + ((lane >> 4) << 2) + r;  // C/D: row=(lane>>4)*4+reg
        long col = n0 + wc * 64 + n * 16 + (lane & 15);              //      col=lane&15
        float h = acc[m][n][r] * inv;
        if constexpr (SPLITK)
          atomicAdd(&out[row * Ntot + col], h);
        else if constexpr (__is_same(OutT, float))
          out[row * Ntot + col] = h;
        else
          out[row * Ntot + col] = __float2bfloat16(h);
      }
}

extern "C" void kernel_launch(void* const* d_in, const int* in_sizes, int n_in, void* d_out,
                              int out_size, void* d_ws, size_t ws_size, hipStream_t stream) {
  const float* x = (const float*)d_in[0];
  const int* idx = (const int*)d_in[1];
  const float* W_K = (const float*)d_in[2];
  const float* W_V = (const float*)d_in[3];
  const float* W_in = (const float*)d_in[4];
  const float* W_out = (const float*)d_in[5];
  float* out = (float*)d_out;  // reference output dtype is float32

  char* ws = (char*)d_ws;
  size_t off = 0;
  unsigned* maxb = (unsigned*)(ws + off); off += 256;
  float* KqT = (float*)(ws + off); off += (size_t)N_KV * D_MODEL * 4;   // [256][2048] f32
  float* VqT = (float*)(ws + off); off += (size_t)N_KV * D_MODEL * 4;
  bf16* QinT = (bf16*)(ws + off); off += (size_t)D_FF * D_MODEL * 2;    // [8192][2048]
  // comb region; QoutT overlays it after GEMM1 (comb dead by then)
  bf16* combHi = (bf16*)(ws + off);
  bf16* QoutT = (bf16*)(ws + off);
  off += (size_t)D_MODEL * D_FF * 2;  // 33.5 MB ([2048][8192])
  bf16* hidHi = (bf16*)(ws + off); off += (size_t)M_ROWS * D_FF * 2;    // 67 MB

  hipMemsetAsync(maxb, 0, 16, stream);
  hipMemsetAsync(out, 0, (size_t)M_ROWS * D_MODEL * 4, stream);  // split-K atomic target
  maxabs4_kernel<<<dim3(512, 4), 256, 0, stream>>>(
      (const float4*)W_K, (D_MODEL * N_KV) / 4, (const float4*)W_V, (D_MODEL * N_KV) / 4,
      (const float4*)W_in, (D_MODEL * D_FF) / 4, (const float4*)W_out, (D_FF * D_MODEL) / 4,
      maxb);

  quantT_f32<<<dim3(N_KV / 64, D_MODEL / 64), 256, 0, stream>>>(W_K, KqT, D_MODEL, N_KV, maxb + 0);
  quantT_f32<<<dim3(N_KV / 64, D_MODEL / 64), 256, 0, stream>>>(W_V, VqT, D_MODEL, N_KV, maxb + 1);
  quantT_bf16<<<dim3(D_FF / 64, D_MODEL / 64), 256, 0, stream>>>(W_in, QinT, D_MODEL, D_FF, maxb + 2);

  attn_kernel<<<M_ROWS, 256, 0, stream>>>(x, idx, KqT, VqT, combHi);

  gemm8<D_MODEL, false, bf16><<<dim3(D_FF / 256, M_ROWS / 256), 512, 0, stream>>>(
      combHi, QinT, maxb + 2, hidHi, D_FF);

  quantT_bf16<<<dim3(D_MODEL / 64, D_FF / 64), 256, 0, stream>>>(W_out, QoutT, D_FF, D_MODEL, maxb + 3);

  gemm8<D_FF, true, float><<<dim3(D_MODEL / 256, M_ROWS / 256, 2), 512, 0, stream>>>(
      hidHi, QoutT, maxb + 3, out, D_MODEL);
}